// Round 7
// baseline (265.602 us; speedup 1.0000x reference)
//
#include <hip/hip_runtime.h>
#include <hip/hip_cooperative_groups.h>

namespace cg = cooperative_groups;

// out[b,n] = 1/(16*50625) * sum_j Acoeff[n,j] * S[b,j]
// S[b,j]   = sum_n Bbasis[j,n] * (M @ T[b,j])[n]
// T[b,j,m] = sum_{p,q,r,s} w[j1][p] w[j2][q] w[j3][r] w[j4][s] * arr[b,p,q,r,s,m]
// w masks (per dim, D=16, L=3, window R=2, stride 1, VALID):
//   class0: 0x36DB  class1: 0x6DB6  class2: 0xDB6C
//
// R6 split = 83.9us. Last lever: the K1->K2 dispatch boundary (~2-3us of
// drain + launch). This merges both into ONE cooperative dispatch. R2's
// failure (absmax 5e-4) is attributed to non-coherent per-XCD L2: plain
// stores/loads across grid.sync. Fix: the V handoff uses AGENT-SCOPE ATOMIC
// stores (write through to LLC) and atomic loads (bypass stale L2) — the
// sanctioned device-scope mechanism. out-zeroing is atomic too, so the final
// LLC atomicAdd RMWs observe it. Phase B math is bit-identical to R6's K2.

static __device__ __forceinline__ void add4(float4& a, const float4& b) {
    a.x += b.x; a.y += b.y; a.z += b.z; a.w += b.w;
}
static __device__ __forceinline__ void fma4(float4& a, float w, const float4& b) {
    a.x = fmaf(w, b.x, a.x); a.y = fmaf(w, b.y, a.y);
    a.z = fmaf(w, b.z, a.z); a.w = fmaf(w, b.w, a.w);
}

__global__ __launch_bounds__(128) void sdd4_all(
    const float* __restrict__ arr,      // [4,16,16,16,16,32]
    const float* __restrict__ Mmat,     // [32,32]
    const float* __restrict__ Bbasis,   // [81,32]
    const float* __restrict__ Acoeff,   // [32,81]
    float* __restrict__ V,              // ws [4][9][256][32]
    float* __restrict__ out)            // [4,32]
{
    __shared__ float4 U_lds[400];        // phase A: [r*25 + cls*8 + mv]
    __shared__ float  M_lds[32 * 33];    // phase B
    __shared__ float  Bb_lds[9 * 33];
    __shared__ float  Vp[4 * 9 * 33];    // [g][c][m]
    __shared__ float  Vs[9 * 33];
    __shared__ float  Y_lds[9 * 33];
    __shared__ float  Sf[9];

    const int t  = threadIdx.x;
    const int bx = blockIdx.x;           // 0..1023
    const int b  = bx >> 8;
    const int p  = (bx >> 4) & 15;
    const int q  = bx & 15;

    // zero out[128] at the coherence point (visible to later LLC atomicAdds)
    if (bx == 0)
        __hip_atomic_store(&out[t], 0.f, __ATOMIC_RELAXED,
                           __HIP_MEMORY_SCOPE_AGENT);

    // ---- phase A: stream tile, s-reduce per class ----
    const int r  = t >> 3;               // 0..15
    const int mv = t & 7;                // float4 index within m
    const float4* A4 = reinterpret_cast<const float4*>(arr);
    const size_t tile = (size_t)((b * 16 + p) * 16 + q) * 2048;

    float4 u0 = make_float4(0.f, 0.f, 0.f, 0.f), u1 = u0, u2 = u0;
    #pragma unroll
    for (int s = 0; s < 16; ++s) {
        float4 x = A4[tile + (size_t)(r * 16 + s) * 8 + mv];
        if ((0x36DBu >> s) & 1) add4(u0, x);
        if ((0x6DB6u >> s) & 1) add4(u1, x);
        if ((0xDB6Cu >> s) & 1) add4(u2, x);
    }
    U_lds[r * 25 +      mv] = u0;
    U_lds[r * 25 +  8 + mv] = u1;
    U_lds[r * 25 + 16 + mv] = u2;
    __syncthreads();

    // r-reduce per class; store V through the LLC (agent-scope atomic stores)
    if (t < 72) {
        const int j3  = t / 24;
        const int rem = t % 24;
        const int j4  = rem >> 3;
        const int mv2 = rem & 7;
        const unsigned msk = (j3 == 0) ? 0x36DBu : (j3 == 1 ? 0x6DB6u : 0xDB6Cu);
        float4 acc = make_float4(0.f, 0.f, 0.f, 0.f);
        #pragma unroll
        for (int rr = 0; rr < 16; ++rr) {
            float w = (float)((msk >> rr) & 1u);
            fma4(acc, w, U_lds[rr * 25 + j4 * 8 + mv2]);
        }
        const int jj = j3 * 3 + j4;
        float* dst = &V[(size_t)(((b * 9 + jj) * 256 + p * 16 + q) * 8 + mv2) * 4];
        __hip_atomic_store(&dst[0], acc.x, __ATOMIC_RELAXED, __HIP_MEMORY_SCOPE_AGENT);
        __hip_atomic_store(&dst[1], acc.y, __ATOMIC_RELAXED, __HIP_MEMORY_SCOPE_AGENT);
        __hip_atomic_store(&dst[2], acc.z, __ATOMIC_RELAXED, __HIP_MEMORY_SCOPE_AGENT);
        __hip_atomic_store(&dst[3], acc.w, __ATOMIC_RELAXED, __HIP_MEMORY_SCOPE_AGENT);
    }

    __threadfence();
    cg::this_grid().sync();

    // ---- phase B (blocks 0..35 = (b,jj)): bit-identical to R6's K2 ----
    if (bx < 36) {
        const int bb = bx / 9;
        const int jj = bx % 9;

        const float4* M4 = reinterpret_cast<const float4*>(Mmat);
        for (int i = t; i < 256; i += 128) {
            float4 v = M4[i];
            float* dst = &M_lds[(i >> 3) * 33 + (i & 7) * 4];
            dst[0] = v.x; dst[1] = v.y; dst[2] = v.z; dst[3] = v.w;
        }
        const float4* B4 = reinterpret_cast<const float4*>(Bbasis);
        if (t < 72) {
            const int k = t >> 3, f4 = t & 7;
            float4 v = B4[(k * 9 + jj) * 8 + f4];
            float* dst = &Bb_lds[k * 33 + f4 * 4];
            dst[0] = v.x; dst[1] = v.y; dst[2] = v.z; dst[3] = v.w;
        }

        // masked (p,q) accumulation: 4 groups x 64 pq, lane owns m
        const int g = t >> 5;            // 0..3
        const int m = t & 31;
        const float* Vb = V + (size_t)bx * 8192;   // [256][32] slab
        float acc[9];
        #pragma unroll
        for (int c = 0; c < 9; ++c) acc[c] = 0.f;
        #pragma unroll 4
        for (int u = 0; u < 64; ++u) {
            const int pq = g * 64 + u;
            const int pp = pq >> 4;
            const int qq = pq & 15;
            const float v = __hip_atomic_load(&Vb[pq * 32 + m], __ATOMIC_RELAXED,
                                              __HIP_MEMORY_SCOPE_AGENT);
            const unsigned e1 = ((0x36DBu >> pp) & 1u) | (((0x6DB6u >> pp) & 1u) << 1)
                              | (((0xDB6Cu >> pp) & 1u) << 2);
            const unsigned e2 = ((0x36DBu >> qq) & 1u) | (((0x6DB6u >> qq) & 1u) << 1)
                              | (((0xDB6Cu >> qq) & 1u) << 2);
            #pragma unroll
            for (int c = 0; c < 9; ++c)
                if (((e1 >> (c / 3)) & 1u) && ((e2 >> (c % 3)) & 1u))
                    acc[c] += v;
        }
        #pragma unroll
        for (int c = 0; c < 9; ++c) Vp[(g * 9 + c) * 33 + m] = acc[c];
        __syncthreads();

        // Vs[c][m] = sum_g Vp[g][c][m]
        for (int o = t; o < 288; o += 128) {
            const int c = o >> 5, mm = o & 31;
            float s = 0.f;
            #pragma unroll
            for (int gg = 0; gg < 4; ++gg) s += Vp[(gg * 9 + c) * 33 + mm];
            Vs[c * 33 + mm] = s;
        }
        __syncthreads();

        // Y[c][n] = sum_m M[n][m] * Vs[c][m]
        for (int o = t; o < 288; o += 128) {
            const int c = o >> 5, n = o & 31;
            float s = 0.f;
            #pragma unroll
            for (int mm = 0; mm < 32; ++mm)
                s = fmaf(M_lds[n * 33 + mm], Vs[c * 33 + mm], s);
            Y_lds[c * 33 + n] = s;
        }
        __syncthreads();

        // Sf[c] = Bbasis[c*9+jj] . Y[c]
        if (t < 9) {
            float s = 0.f;
            #pragma unroll
            for (int n = 0; n < 32; ++n)
                s = fmaf(Bb_lds[t * 33 + n], Y_lds[t * 33 + n], s);
            Sf[t] = s;
        }
        __syncthreads();

        // fold Acoeff for this jj; one 32-lane atomic vector per block
        if (t < 32) {
            float z = 0.f;
            #pragma unroll
            for (int c = 0; c < 9; ++c)
                z = fmaf(Acoeff[t * 81 + c * 9 + jj], Sf[c], z);
            atomicAdd(&out[bb * 32 + t], z * (1.0f / 810000.0f));  // 1/(16*15^4)
        }
    }
}

extern "C" void kernel_launch(void* const* d_in, const int* in_sizes, int n_in,
                              void* d_out, int out_size, void* d_ws, size_t ws_size,
                              hipStream_t stream) {
    const float* arr    = (const float*)d_in[0];  // [4,16,16,16,16,32]
    const float* Mmat   = (const float*)d_in[1];  // [32,32]
    const float* Acoeff = (const float*)d_in[2];  // [32,81]
    const float* Bbasis = (const float*)d_in[3];  // [81,32]
    float* V    = (float*)d_ws;                   // 4*9*256*32 floats = 1.18 MB
    float* outp = (float*)d_out;

    void* args[] = {(void*)&arr, (void*)&Mmat, (void*)&Bbasis,
                    (void*)&Acoeff, (void*)&V, (void*)&outp};
    hipLaunchCooperativeKernel((void*)sdd4_all, dim3(1024), dim3(128),
                               args, 0, stream);
}

// Round 8
// 85.094 us; speedup vs baseline: 3.1213x; 3.1213x over previous
//
#include <hip/hip_runtime.h>

// out[b,n] = 1/(16*50625) * sum_j Acoeff[n,j] * S[b,j]
// S[b,j]   = sum_n Bbasis[j,n] * (M @ T[b,j])[n]
// T[b,j,m] = sum_{p,q,r,s} w[j1][p] w[j2][q] w[j3][r] w[j4][s] * arr[b,p,q,r,s,m]
// w masks (per dim, D=16, L=3, window R=2, stride 1, VALID):
//   class0: 0x36DB  class1: 0x6DB6  class2: 0xDB6C
//
// FINAL STRUCTURE (= R6, measured 83.9us, absmax 0.0). Session findings:
//  - Budget: ws-poison fill 44.5us + per-iteration harness fixed ~29.5us
//    (invariant across 2..5-dispatch variants, R0-R6) + K1 ~6us (32MiB
//    compulsory stream, floor 5.5us) + K2+boundary ~3us. Floor ~81us.
//  - R4 replicas: monolithic fused kernel = 13.6us warm (tail-serialized);
//    splitting the tail into K2 behind a dispatch boundary -> 83.9us total.
//  - R7: in-kernel grid-wide handoff is NOT viable: cooperative grid.sync +
//    agent-scope atomic V handoff = 172us (VALUBusy 0.5%, spin-wait +
//    unpipelined atomic loads). R2: plain loads across grid.sync = WRONG
//    (per-XCD L2 non-coherence, absmax 5e-4). Dispatch boundaries ARE the
//    cheap cross-XCD release/acquire (end-of-kernel L2 writeback/inv).
//   K1 (1024 blks = (b,p,q)): pure stream -> s-reduce -> r-reduce -> direct
//       global store of V[b][jj][p][q][m] (1.18MB ws). 1 barrier, no atomics.
//   K2 (36 blks = (b,jj)): contiguous 32KB V slab -> 9 mask-weighted (i1,i2)
//       sums over (p,q) -> M matvecs -> Bbasis dots -> Acoeff fold -> one
//       32-lane atomicAdd per block (1.2K RMWs total).

static __device__ __forceinline__ void add4(float4& a, const float4& b) {
    a.x += b.x; a.y += b.y; a.z += b.z; a.w += b.w;
}
static __device__ __forceinline__ void fma4(float4& a, float w, const float4& b) {
    a.x = fmaf(w, b.x, a.x); a.y = fmaf(w, b.y, a.y);
    a.z = fmaf(w, b.z, a.z); a.w = fmaf(w, b.w, a.w);
}

__global__ __launch_bounds__(128) void sdd4_v(
    const float* __restrict__ arr,      // [4,16,16,16,16,32]
    float* __restrict__ V,              // [4][9][16][16][32] ws
    float* __restrict__ out)            // [4,32] zeroed here (block 0)
{
    __shared__ float4 U_lds[400];        // [r*25 + cls*8 + mv]  (pad 24->25)

    const int t  = threadIdx.x;
    const int bx = blockIdx.x;           // 0..1023
    const int b  = bx >> 8;
    const int p  = (bx >> 4) & 15;
    const int q  = bx & 15;

    if (bx == 0) out[t] = 0.f;           // visible to K2 via dispatch boundary

    const int r  = t >> 3;               // 0..15
    const int mv = t & 7;                // float4 index within m
    const float4* A4 = reinterpret_cast<const float4*>(arr);
    const size_t tile = (size_t)((b * 16 + p) * 16 + q) * 2048;

    float4 u0 = make_float4(0.f, 0.f, 0.f, 0.f), u1 = u0, u2 = u0;
    #pragma unroll
    for (int s = 0; s < 16; ++s) {
        float4 x = A4[tile + (size_t)(r * 16 + s) * 8 + mv];
        if ((0x36DBu >> s) & 1) add4(u0, x);
        if ((0x6DB6u >> s) & 1) add4(u1, x);
        if ((0xDB6Cu >> s) & 1) add4(u2, x);
    }
    U_lds[r * 25 +      mv] = u0;
    U_lds[r * 25 +  8 + mv] = u1;
    U_lds[r * 25 + 16 + mv] = u2;
    __syncthreads();

    // r-reduce per class; each active lane stores its float4 straight to V
    if (t < 72) {
        const int j3  = t / 24;
        const int rem = t % 24;
        const int j4  = rem >> 3;
        const int mv2 = rem & 7;
        const unsigned msk = (j3 == 0) ? 0x36DBu : (j3 == 1 ? 0x6DB6u : 0xDB6Cu);
        float4 acc = make_float4(0.f, 0.f, 0.f, 0.f);
        #pragma unroll
        for (int rr = 0; rr < 16; ++rr) {
            float w = (float)((msk >> rr) & 1u);
            fma4(acc, w, U_lds[rr * 25 + j4 * 8 + mv2]);
        }
        const int jj = j3 * 3 + j4;
        float4* V4 = reinterpret_cast<float4*>(V);
        V4[((b * 9 + jj) * 256 + p * 16 + q) * 8 + mv2] = acc;
    }
}

__global__ __launch_bounds__(256) void sdd4_reduce(
    const float* __restrict__ V,        // [4][9][256][32] ws
    const float* __restrict__ Mmat,     // [32,32]
    const float* __restrict__ Bbasis,   // [81,32]
    const float* __restrict__ Acoeff,   // [32,81]
    float* __restrict__ out)            // [4,32] pre-zeroed by K1
{
    __shared__ float M_lds[32 * 33];
    __shared__ float Bb_lds[9 * 33];
    __shared__ float Vp[8 * 9 * 33];     // per-group partial [g][c][m]
    __shared__ float Vs[9 * 33];         // [c][m]
    __shared__ float Y_lds[9 * 33];      // [c][n]
    __shared__ float Sf[9];

    const int t   = threadIdx.x;         // 0..255
    const int blk = blockIdx.x;          // 0..35
    const int b   = blk / 9;
    const int jj  = blk % 9;

    // stage M (padded) and the 9 Bbasis rows jf = c*9 + jj
    const float4* M4 = reinterpret_cast<const float4*>(Mmat);
    if (t < 256) {
        float4 v = M4[t];
        float* dst = &M_lds[(t >> 3) * 33 + (t & 7) * 4];
        dst[0] = v.x; dst[1] = v.y; dst[2] = v.z; dst[3] = v.w;
    }
    const float4* B4 = reinterpret_cast<const float4*>(Bbasis);
    if (t < 72) {
        const int k = t >> 3, f4 = t & 7;
        float4 v = B4[(k * 9 + jj) * 8 + f4];
        float* dst = &Bb_lds[k * 33 + f4 * 4];
        dst[0] = v.x; dst[1] = v.y; dst[2] = v.z; dst[3] = v.w;
    }

    // masked (p,q) accumulation: 8 groups x 32 pq each, lane owns m
    const int g = t >> 5;                // 0..7
    const int m = t & 31;
    const float* Vb = V + (size_t)blk * 8192;   // [256][32] slab
    float acc[9];
    #pragma unroll
    for (int c = 0; c < 9; ++c) acc[c] = 0.f;
    #pragma unroll 4
    for (int u = 0; u < 32; ++u) {
        const int pq = g * 32 + u;
        const int p  = pq >> 4;
        const int q  = pq & 15;
        const float v = Vb[pq * 32 + m];
        const unsigned e1 = ((0x36DBu >> p) & 1u) | (((0x6DB6u >> p) & 1u) << 1)
                          | (((0xDB6Cu >> p) & 1u) << 2);
        const unsigned e2 = ((0x36DBu >> q) & 1u) | (((0x6DB6u >> q) & 1u) << 1)
                          | (((0xDB6Cu >> q) & 1u) << 2);
        #pragma unroll
        for (int c = 0; c < 9; ++c)
            if (((e1 >> (c / 3)) & 1u) && ((e2 >> (c % 3)) & 1u))
                acc[c] += v;
    }
    #pragma unroll
    for (int c = 0; c < 9; ++c) Vp[(g * 9 + c) * 33 + m] = acc[c];
    __syncthreads();

    // Vs[c][m] = sum_g Vp[g][c][m]
    for (int o = t; o < 288; o += 256) {
        const int c = o >> 5, mm = o & 31;
        float s = 0.f;
        #pragma unroll
        for (int gg = 0; gg < 8; ++gg) s += Vp[(gg * 9 + c) * 33 + mm];
        Vs[c * 33 + mm] = s;
    }
    __syncthreads();

    // Y[c][n] = sum_m M[n][m] * Vs[c][m]
    for (int o = t; o < 288; o += 256) {
        const int c = o >> 5, n = o & 31;
        float s = 0.f;
        #pragma unroll
        for (int mm = 0; mm < 32; ++mm)
            s = fmaf(M_lds[n * 33 + mm], Vs[c * 33 + mm], s);
        Y_lds[c * 33 + n] = s;
    }
    __syncthreads();

    // Sf[c] = Bbasis[c*9+jj] . Y[c]
    if (t < 9) {
        float s = 0.f;
        #pragma unroll
        for (int n = 0; n < 32; ++n)
            s = fmaf(Bb_lds[t * 33 + n], Y_lds[t * 33 + n], s);
        Sf[t] = s;
    }
    __syncthreads();

    // fold Acoeff for this jj; one 32-lane atomic vector per block (36 total)
    if (t < 32) {
        float z = 0.f;
        #pragma unroll
        for (int c = 0; c < 9; ++c)
            z = fmaf(Acoeff[t * 81 + c * 9 + jj], Sf[c], z);
        atomicAdd(&out[b * 32 + t], z * (1.0f / 810000.0f));  // 1/(16*15^4)
    }
}

extern "C" void kernel_launch(void* const* d_in, const int* in_sizes, int n_in,
                              void* d_out, int out_size, void* d_ws, size_t ws_size,
                              hipStream_t stream) {
    const float* arr    = (const float*)d_in[0];  // [4,16,16,16,16,32]
    const float* Mmat   = (const float*)d_in[1];  // [32,32]
    const float* Acoeff = (const float*)d_in[2];  // [32,81]
    const float* Bbasis = (const float*)d_in[3];  // [81,32]
    float* V = (float*)d_ws;                      // 4*9*256*32 floats = 1.18 MB

    sdd4_v     <<<dim3(1024), dim3(128), 0, stream>>>(arr, V, (float*)d_out);
    sdd4_reduce<<<dim3(36),   dim3(256), 0, stream>>>(V, Mmat, Bbasis, Acoeff,
                                                      (float*)d_out);
}